// Round 13
// baseline (119.648 us; speedup 1.0000x reference)
//
#include <hip/hip_runtime.h>

// MPS classifier: logits[b,o] = (v/||v||)·cls[o] + log||v||,
//   v = head0(b) · M_1(b) · ... · M_783(b),  M_n = A_n + x[b,n]*(B_n - A_n).
// Chain associative; normalizations telescope.
//
// K1 (chunk_kernel): f16 chain (v_pk_fma_f16 on raw `unsigned` f16x2 bit
//   patterns), 2 LANES PER SAMPLE with [5][5] chain arrays -- the ONLY
//   register shape the allocator has never spilled (r5: VGPR 88 clean;
//   every [10][5] variant spilled: r2/r7/r9/r12). L=8 sites/chunk (C=98):
//   grid 1568 blocks -> ~6 blocks/CU resident (was 3) to close the
//   latency gap between measured 46us and the 24.5us LDS-pipe floor.
//   Weights fused-converted into LDS with exact x2.0 pre-scale (corrected
//   via lbuf -= ns*ln2): 25 ds_read_b128/site/wave.
// K2 (combine_kernel): pbuf packed f16 dwords [c][b][50] (40 MB total, same
//   as proven-safe); for output column jj the dword index is i*5 + jj/2
//   with constant half jj&1 -> 10 stride-5 dword loads per chunk. 16
//   samples per 256-thread block (launch_bounds(256,2): ring fits in regs),
//   depth-8 prefetch ring, renorm deferred to every 8th chunk.

constexpr int Bsz = 2048;
constexpr int Nn  = 784;
constexpr int NS  = 783;
constexpr int LCH = 8;      // sites per chunk

// packed-f16 VOP3P on raw i32 registers (semantics proven r9-r12).
#define PKH_FMA(d, a, b, c) \
  asm("v_pk_fma_f16 %0, %1, %2, %3" : "=v"(d) : "v"(a), "v"(b), "v"(c))
#define PKH_ACC_LO(d, m, s) \
  asm("v_pk_fma_f16 %0, %1, %2, %0 op_sel:[0,0,0] op_sel_hi:[1,0,1]" \
      : "+v"(d) : "v"(m), "v"(s))
#define PKH_ACC_HI(d, m, s) \
  asm("v_pk_fma_f16 %0, %1, %2, %0 op_sel:[0,1,0] op_sel_hi:[1,1,1]" \
      : "+v"(d) : "v"(m), "v"(s))
#define PKH_MUL_LO(d, m, s) \
  asm("v_pk_mul_f16 %0, %1, %2 op_sel:[0,0] op_sel_hi:[1,0]" \
      : "=v"(d) : "v"(m), "v"(s))

__device__ __forceinline__ unsigned short f2h_bits(float f) {
    union { _Float16 h; unsigned short u; } c;
    c.h = (_Float16)f;
    return c.u;
}
__device__ __forceinline__ float hlo(unsigned u) {
    union { unsigned short s; _Float16 h; } c;
    c.s = (unsigned short)(u & 0xffff);
    return (float)c.h;
}
__device__ __forceinline__ float hhi(unsigned u) {
    union { unsigned short s; _Float16 h; } c;
    c.s = (unsigned short)(u >> 16);
    return (float)c.h;
}

// dst(5x10) = src(5x10) * M(site); M blended row-pair at a time from LDS.
// ws = site base in s_w (100 dwords; pair s=(i*5+q) -> dwords 2s{A}, 2s+1{D})
__device__ __forceinline__ void site_step(const unsigned* __restrict__ ws,
                                          const unsigned x2,
                                          const unsigned (&src)[5][5],
                                          unsigned (&dst)[5][5]) {
#pragma unroll
    for (int ip = 0; ip < 5; ++ip) {
        unsigned m[10];   // m[2t],m[2t+1]: M rows 2ip / 2ip+1, pair t
        const uint4* w4 = (const uint4*)(ws + ip * 20);
#pragma unroll
        for (int t = 0; t < 5; ++t) {
            const uint4 w = w4[t];
            PKH_FMA(m[2 * t],     w.y, x2, w.x);
            PKH_FMA(m[2 * t + 1], w.w, x2, w.z);
        }
#pragma unroll
        for (int r = 0; r < 5; ++r) {
            if (ip == 0) {
#pragma unroll
                for (int q = 0; q < 5; ++q) PKH_MUL_LO(dst[r][q], m[q], src[r][0]);
            } else {
#pragma unroll
                for (int q = 0; q < 5; ++q) PKH_ACC_LO(dst[r][q], m[q], src[r][ip]);
            }
#pragma unroll
            for (int q = 0; q < 5; ++q) PKH_ACC_HI(dst[r][q], m[5 + q], src[r][ip]);
        }
    }
}

// ---------------- K1: f16 chain, 2 lanes per sample, L=8 ------------------
__global__ __launch_bounds__(256, 4) void chunk_kernel(
    const float* __restrict__ x, const float* __restrict__ cores,
    unsigned* __restrict__ pbuf, float* __restrict__ lbuf) {
    __shared__ unsigned s_w[LCH * 100];  // per-site f16 {A,D} dwords (3.2 KB)
    __shared__ float    s_x[128 * 9];    // x slice, stride 9 (4.6 KB)

    const int c   = blockIdx.y;
    const int n0  = 1 + c * LCH;
    const int n1  = min(n0 + LCH, Nn);
    const int ns  = n1 - n0;
    const int tid = (int)threadIdx.x;
    const int b0  = (int)blockIdx.x * 128;

    // stage + convert weights (fused repack): pair e=(k,s), s=(i*5+q)
    for (int e = tid; e < ns * 50; e += 256) {
        const int k = e / 50, s = e - k * 50;
        const int i = s / 5, q = s - i * 5;
        const float* g = cores + (size_t)(n0 - 1 + k) * 200 + i * 20 + 2 * q;
        const float a0 = g[0], a1 = g[1], bb0 = g[10], bb1 = g[11];
        const unsigned A = ((unsigned)f2h_bits(2.f * a1) << 16) | f2h_bits(2.f * a0);
        const unsigned D = ((unsigned)f2h_bits(2.f * (bb1 - a1)) << 16) |
                           f2h_bits(2.f * (bb0 - a0));
        s_w[k * 100 + 2 * s]     = A;
        s_w[k * 100 + 2 * s + 1] = D;
    }
    // stage x slice (coalesced 8-wide)
    for (int e = tid; e < 128 * 8; e += 256) {
        const int bl = e >> 3, k = e & 7;
        if (k < ns) s_x[bl * 9 + k] = x[(size_t)(b0 + bl) * Nn + n0 + k];
    }
    __syncthreads();

    const int h = tid & 1;              // row-half owner
    const int u = tid >> 1;             // sample slot 0..127
    const int b = b0 + u;
    const float* __restrict__ xs = s_x + u * 9;

    unsigned p[5][5], q2[5][5];
    {   // first site: P = 2*M (rows 5h..5h+4)
        const unsigned short xb = f2h_bits(xs[0]);
        const unsigned x2 = ((unsigned)xb << 16) | xb;
#pragma unroll
        for (int r = 0; r < 5; ++r)
#pragma unroll
            for (int q = 0; q < 5; ++q) {
                const unsigned A = s_w[(5 * h + r) * 10 + 2 * q];
                const unsigned D = s_w[(5 * h + r) * 10 + 2 * q + 1];
                PKH_FMA(p[r][q], D, x2, A);
            }
    }
    int k = 1;
    while (k + 1 < ns) {        // ping-pong pairs, no copies
        {
            const unsigned short xb = f2h_bits(xs[k]);
            site_step(s_w + k * 100, ((unsigned)xb << 16) | xb, p, q2);
        }
        {
            const unsigned short xb = f2h_bits(xs[k + 1]);
            site_step(s_w + (k + 1) * 100, ((unsigned)xb << 16) | xb, q2, p);
        }
        k += 2;
    }
    if (k < ns) {               // tail site
        const unsigned short xb = f2h_bits(xs[k]);
        site_step(s_w + k * 100, ((unsigned)xb << 16) | xb, p, q2);
#pragma unroll
        for (int r = 0; r < 5; ++r)
#pragma unroll
            for (int q = 0; q < 5; ++q) p[r][q] = q2[r][q];
    }

    // Frobenius renorm (f32 accumulate, pair-reduce across the 2 lanes);
    // correct the 2^ns pre-scale in lbuf.
    float ss = 0.f;
#pragma unroll
    for (int r = 0; r < 5; ++r)
#pragma unroll
        for (int q = 0; q < 5; ++q) {
            const float lo = hlo(p[r][q]), hi = hhi(p[r][q]);
            ss = fmaf(lo, lo, ss);
            ss = fmaf(hi, hi, ss);
        }
    ss += __shfl_xor(ss, 1);
    ss = fmaxf(ss, 1e-30f);
    const float rin = rsqrtf(ss);
    if (h == 0)
        lbuf[(size_t)c * Bsz + b] = 0.5f * __logf(ss) - (float)ns * 0.69314718056f;

    // store packed f16 dwords: pbuf[(c*Bsz+b)*50 + (5h+r)*5 + q]
    unsigned* dst = pbuf + ((size_t)c * Bsz + b) * 50;
#pragma unroll
    for (int r = 0; r < 5; ++r)
#pragma unroll
        for (int q = 0; q < 5; ++q) {
            const float lo = hlo(p[r][q]) * rin;
            const float hi = hhi(p[r][q]) * rin;
            dst[(5 * h + r) * 5 + q] =
                ((unsigned)f2h_bits(hi) << 16) | f2h_bits(lo);
        }
}

// ---------------- K2: combine chunks + logits (16 lanes per sample) --------
__global__ __launch_bounds__(256, 2) void combine_kernel(
    const float* __restrict__ x, const float* __restrict__ core0,
    const float* __restrict__ cls, const unsigned* __restrict__ pbuf,
    const float* __restrict__ lbuf, float* __restrict__ out, int C) {
    const int tid   = (int)threadIdx.x;
    const int j     = tid & 15;
    const int jj    = (j < 10) ? j : 9;
    const int gbase = tid & 48;
    const int b     = blockIdx.x * 16 + (tid >> 4);
    const int qoff  = jj >> 1;          // dword offset within row
    const int half  = jj & 1;           // constant half select (i*10 even)

    float v[10];
    const float x0 = x[(size_t)b * Nn];
#pragma unroll
    for (int i = 0; i < 10; ++i) {
        const float c0 = core0[i], c1 = core0[10 + i];
        v[i] = fmaf(x0, c1 - c0, c0);
    }

    // depth-8 prefetch ring, statically indexed; 10 stride-5 dword loads
    float w[8][10];
#pragma unroll
    for (int k8 = 0; k8 < 8; ++k8) {
        if (k8 < C) {
            const unsigned* pn = pbuf + ((size_t)k8 * Bsz + b) * 50 + qoff;
#pragma unroll
            for (int i = 0; i < 10; ++i) {
                const unsigned d = pn[i * 5];
                w[k8][i] = half ? hhi(d) : hlo(d);
            }
        }
    }

    float llog = 0.f;
    for (int cg = 0; cg < C; cg += 8) {
#pragma unroll
        for (int k8 = 0; k8 < 8; ++k8) {
            const int c = cg + k8;
            if (c >= C) break;
            float acc = 0.f;
#pragma unroll
            for (int i = 0; i < 10; ++i) acc = fmaf(v[i], w[k8][i], acc);
            if (j >= 10) acc = 0.f;
            llog += lbuf[(size_t)c * Bsz + b];
            if (k8 == 7 || c == C - 1) {   // deferred renorm
                float s = acc * acc;
                s += __shfl_xor(s, 1);
                s += __shfl_xor(s, 2);
                s += __shfl_xor(s, 4);
                s += __shfl_xor(s, 8);
                s = fmaxf(s, 1e-30f);
                llog += 0.5f * __logf(s);
                acc *= rsqrtf(s);
            }
#pragma unroll
            for (int i = 0; i < 10; ++i) v[i] = __shfl(acc, gbase + i);
            if (c + 8 < C) {               // refill the slot just consumed
                const unsigned* pn =
                    pbuf + ((size_t)(c + 8) * Bsz + b) * 50 + qoff;
#pragma unroll
                for (int i = 0; i < 10; ++i) {
                    const unsigned d = pn[i * 5];
                    w[k8][i] = half ? hhi(d) : hlo(d);
                }
            }
        }
    }

    if (j < 10) {
        float acc = llog;
#pragma unroll
        for (int i = 0; i < 10; ++i) acc = fmaf(v[i], cls[j * 10 + i], acc);
        out[(size_t)b * 10 + j] = acc;
    }
}

// ---------------- launch ----------------
extern "C" void kernel_launch(void* const* d_in, const int* in_sizes, int n_in,
                              void* d_out, int out_size, void* d_ws, size_t ws_size,
                              hipStream_t stream) {
    const float* x     = (const float*)d_in[0];
    const float* core0 = (const float*)d_in[1];
    const float* cores = (const float*)d_in[2];
    const float* cls   = (const float*)d_in[3];
    float* out = (float*)d_out;

    const int C = (NS + LCH - 1) / LCH;        // 98
    unsigned* pbuf = (unsigned*)d_ws;          // C*Bsz*50 dwords = 40.1 MB
    float*    lbuf = (float*)(pbuf + (size_t)C * 50 * Bsz);

    hipLaunchKernelGGL(chunk_kernel, dim3(Bsz / 128, C), dim3(256),
                       0, stream, x, cores, pbuf, lbuf);
    hipLaunchKernelGGL(combine_kernel, dim3(Bsz / 16), dim3(256),
                       0, stream, x, core0, cls, pbuf, lbuf, out, C);
}

// Round 14
// 118.176 us; speedup vs baseline: 1.0125x; 1.0125x over previous
//
#include <hip/hip_runtime.h>

// MPS classifier: logits[b,o] = (v/||v||)·cls[o] + log||v||,
//   v = head0(b) · M_1(b) · ... · M_783(b),  M_n = A_n + x[b,n]*(B_n - A_n).
// Chain associative; normalizations telescope.
//
// K1 (chunk_kernel, == r13): f16 chain (v_pk_fma_f16 on raw `unsigned`
//   f16x2 bit patterns), 2 lanes per sample, [5][5] arrays (the only
//   never-spilled shape), L=8 sites/chunk (C=98), launch_bounds(256,4)
//   -> ~6 blocks/CU. Weights fused-converted to LDS with exact x2.0
//   pre-scale (corrected via lbuf -= ns*ln2). Measured ~40us.
// K2 (combine_kernel): depth-8 prefetch ring of RAW PACKED DWORDS with
//   union-free unpack (integer shift at refill + opaque v_cvt_f32_f16 asm
//   at use). r13's union-based hhi/hlo unpack collapsed allocation to
//   VGPR=56 and dismantled the prefetch (76us at 4% VALU); every
//   union-free raw-unsigned path in this session has built clean.

constexpr int Bsz = 2048;
constexpr int Nn  = 784;
constexpr int NS  = 783;
constexpr int LCH = 8;      // sites per chunk

// packed-f16 VOP3P on raw i32 registers (semantics proven r9-r13).
#define PKH_FMA(d, a, b, c) \
  asm("v_pk_fma_f16 %0, %1, %2, %3" : "=v"(d) : "v"(a), "v"(b), "v"(c))
#define PKH_ACC_LO(d, m, s) \
  asm("v_pk_fma_f16 %0, %1, %2, %0 op_sel:[0,0,0] op_sel_hi:[1,0,1]" \
      : "+v"(d) : "v"(m), "v"(s))
#define PKH_ACC_HI(d, m, s) \
  asm("v_pk_fma_f16 %0, %1, %2, %0 op_sel:[0,1,0] op_sel_hi:[1,1,1]" \
      : "+v"(d) : "v"(m), "v"(s))
#define PKH_MUL_LO(d, m, s) \
  asm("v_pk_mul_f16 %0, %1, %2 op_sel:[0,0] op_sel_hi:[1,0]" \
      : "=v"(d) : "v"(m), "v"(s))
// f16 (bits[15:0] of u) -> f32, opaque to the optimizer
#define CVT_H2F(f, u) asm("v_cvt_f32_f16 %0, %1" : "=v"(f) : "v"(u))

__device__ __forceinline__ unsigned short f2h_bits(float f) {
    union { _Float16 h; unsigned short u; } c;
    c.h = (_Float16)f;
    return c.u;
}
// K1-epilogue-only unpack (K1 builds clean with these; K2 must NOT use them)
__device__ __forceinline__ float hlo(unsigned u) {
    union { unsigned short s; _Float16 h; } c;
    c.s = (unsigned short)(u & 0xffff);
    return (float)c.h;
}
__device__ __forceinline__ float hhi(unsigned u) {
    union { unsigned short s; _Float16 h; } c;
    c.s = (unsigned short)(u >> 16);
    return (float)c.h;
}

// dst(5x10) = src(5x10) * M(site); M blended row-pair at a time from LDS.
__device__ __forceinline__ void site_step(const unsigned* __restrict__ ws,
                                          const unsigned x2,
                                          const unsigned (&src)[5][5],
                                          unsigned (&dst)[5][5]) {
#pragma unroll
    for (int ip = 0; ip < 5; ++ip) {
        unsigned m[10];   // m[2t],m[2t+1]: M rows 2ip / 2ip+1, pair t
        const uint4* w4 = (const uint4*)(ws + ip * 20);
#pragma unroll
        for (int t = 0; t < 5; ++t) {
            const uint4 w = w4[t];
            PKH_FMA(m[2 * t],     w.y, x2, w.x);
            PKH_FMA(m[2 * t + 1], w.w, x2, w.z);
        }
#pragma unroll
        for (int r = 0; r < 5; ++r) {
            if (ip == 0) {
#pragma unroll
                for (int q = 0; q < 5; ++q) PKH_MUL_LO(dst[r][q], m[q], src[r][0]);
            } else {
#pragma unroll
                for (int q = 0; q < 5; ++q) PKH_ACC_LO(dst[r][q], m[q], src[r][ip]);
            }
#pragma unroll
            for (int q = 0; q < 5; ++q) PKH_ACC_HI(dst[r][q], m[5 + q], src[r][ip]);
        }
    }
}

// ---------------- K1: f16 chain, 2 lanes per sample, L=8 ------------------
__global__ __launch_bounds__(256, 4) void chunk_kernel(
    const float* __restrict__ x, const float* __restrict__ cores,
    unsigned* __restrict__ pbuf, float* __restrict__ lbuf) {
    __shared__ unsigned s_w[LCH * 100];  // per-site f16 {A,D} dwords
    __shared__ float    s_x[128 * 9];    // x slice, stride 9

    const int c   = blockIdx.y;
    const int n0  = 1 + c * LCH;
    const int n1  = min(n0 + LCH, Nn);
    const int ns  = n1 - n0;
    const int tid = (int)threadIdx.x;
    const int b0  = (int)blockIdx.x * 128;

    for (int e = tid; e < ns * 50; e += 256) {
        const int k = e / 50, s = e - k * 50;
        const int i = s / 5, q = s - i * 5;
        const float* g = cores + (size_t)(n0 - 1 + k) * 200 + i * 20 + 2 * q;
        const float a0 = g[0], a1 = g[1], bb0 = g[10], bb1 = g[11];
        const unsigned A = ((unsigned)f2h_bits(2.f * a1) << 16) | f2h_bits(2.f * a0);
        const unsigned D = ((unsigned)f2h_bits(2.f * (bb1 - a1)) << 16) |
                           f2h_bits(2.f * (bb0 - a0));
        s_w[k * 100 + 2 * s]     = A;
        s_w[k * 100 + 2 * s + 1] = D;
    }
    for (int e = tid; e < 128 * 8; e += 256) {
        const int bl = e >> 3, k = e & 7;
        if (k < ns) s_x[bl * 9 + k] = x[(size_t)(b0 + bl) * Nn + n0 + k];
    }
    __syncthreads();

    const int h = tid & 1;
    const int u = tid >> 1;
    const int b = b0 + u;
    const float* __restrict__ xs = s_x + u * 9;

    unsigned p[5][5], q2[5][5];
    {   // first site: P = 2*M (rows 5h..5h+4)
        const unsigned short xb = f2h_bits(xs[0]);
        const unsigned x2 = ((unsigned)xb << 16) | xb;
#pragma unroll
        for (int r = 0; r < 5; ++r)
#pragma unroll
            for (int q = 0; q < 5; ++q) {
                const unsigned A = s_w[(5 * h + r) * 10 + 2 * q];
                const unsigned D = s_w[(5 * h + r) * 10 + 2 * q + 1];
                PKH_FMA(p[r][q], D, x2, A);
            }
    }
    int k = 1;
    while (k + 1 < ns) {
        {
            const unsigned short xb = f2h_bits(xs[k]);
            site_step(s_w + k * 100, ((unsigned)xb << 16) | xb, p, q2);
        }
        {
            const unsigned short xb = f2h_bits(xs[k + 1]);
            site_step(s_w + (k + 1) * 100, ((unsigned)xb << 16) | xb, q2, p);
        }
        k += 2;
    }
    if (k < ns) {
        const unsigned short xb = f2h_bits(xs[k]);
        site_step(s_w + k * 100, ((unsigned)xb << 16) | xb, p, q2);
#pragma unroll
        for (int r = 0; r < 5; ++r)
#pragma unroll
            for (int q = 0; q < 5; ++q) p[r][q] = q2[r][q];
    }

    float ss = 0.f;
#pragma unroll
    for (int r = 0; r < 5; ++r)
#pragma unroll
        for (int q = 0; q < 5; ++q) {
            const float lo = hlo(p[r][q]), hi = hhi(p[r][q]);
            ss = fmaf(lo, lo, ss);
            ss = fmaf(hi, hi, ss);
        }
    ss += __shfl_xor(ss, 1);
    ss = fmaxf(ss, 1e-30f);
    const float rin = rsqrtf(ss);
    if (h == 0)
        lbuf[(size_t)c * Bsz + b] = 0.5f * __logf(ss) - (float)ns * 0.69314718056f;

    unsigned* dst = pbuf + ((size_t)c * Bsz + b) * 50;
#pragma unroll
    for (int r = 0; r < 5; ++r)
#pragma unroll
        for (int q = 0; q < 5; ++q) {
            const float lo = hlo(p[r][q]) * rin;
            const float hi = hhi(p[r][q]) * rin;
            dst[(5 * h + r) * 5 + q] =
                ((unsigned)f2h_bits(hi) << 16) | f2h_bits(lo);
        }
}

// ---------------- K2: combine chunks + logits (16 lanes per sample) --------
// Ring holds raw packed dwords, pre-shifted so bits[15:0] = my element;
// cvt at use via opaque v_cvt_f32_f16 asm. NO unions in this kernel.
__global__ __launch_bounds__(256, 2) void combine_kernel(
    const float* __restrict__ x, const float* __restrict__ core0,
    const float* __restrict__ cls, const unsigned* __restrict__ pbuf,
    const float* __restrict__ lbuf, float* __restrict__ out, int C) {
    const int tid   = (int)threadIdx.x;
    const int j     = tid & 15;
    const int jj    = (j < 10) ? j : 9;
    const int gbase = tid & 48;
    const int b     = blockIdx.x * 16 + (tid >> 4);
    const int qoff  = jj >> 1;               // dword offset within row
    const unsigned sh = (unsigned)(jj & 1) * 16;  // shift to bring my half low

    float v[10];
    const float x0 = x[(size_t)b * Nn];
#pragma unroll
    for (int i = 0; i < 10; ++i) {
        const float c0 = core0[i], c1 = core0[10 + i];
        v[i] = fmaf(x0, c1 - c0, c0);
    }

    unsigned u8[8][10];     // depth-8 prefetch ring (packed, pre-shifted)
#pragma unroll
    for (int k8 = 0; k8 < 8; ++k8) {
        if (k8 < C) {
            const unsigned* pn = pbuf + ((size_t)k8 * Bsz + b) * 50 + qoff;
#pragma unroll
            for (int i = 0; i < 10; ++i) u8[k8][i] = pn[i * 5] >> sh;
        }
    }

    float llog = 0.f;
    for (int cg = 0; cg < C; cg += 8) {
#pragma unroll
        for (int k8 = 0; k8 < 8; ++k8) {
            const int c = cg + k8;
            if (c >= C) break;
            float acc = 0.f;
#pragma unroll
            for (int i = 0; i < 10; ++i) {
                float wv;
                CVT_H2F(wv, u8[k8][i]);
                acc = fmaf(v[i], wv, acc);
            }
            if (j >= 10) acc = 0.f;
            llog += lbuf[(size_t)c * Bsz + b];
            if (k8 == 7 || c == C - 1) {   // deferred renorm
                float s = acc * acc;
                s += __shfl_xor(s, 1);
                s += __shfl_xor(s, 2);
                s += __shfl_xor(s, 4);
                s += __shfl_xor(s, 8);
                s = fmaxf(s, 1e-30f);
                llog += 0.5f * __logf(s);
                acc *= rsqrtf(s);
            }
#pragma unroll
            for (int i = 0; i < 10; ++i) v[i] = __shfl(acc, gbase + i);
            if (c + 8 < C) {               // refill the slot just consumed
                const unsigned* pn =
                    pbuf + ((size_t)(c + 8) * Bsz + b) * 50 + qoff;
#pragma unroll
                for (int i = 0; i < 10; ++i) u8[k8][i] = pn[i * 5] >> sh;
            }
        }
    }

    if (j < 10) {
        float acc = llog;
#pragma unroll
        for (int i = 0; i < 10; ++i) acc = fmaf(v[i], cls[j * 10 + i], acc);
        out[(size_t)b * 10 + j] = acc;
    }
}

// ---------------- launch ----------------
extern "C" void kernel_launch(void* const* d_in, const int* in_sizes, int n_in,
                              void* d_out, int out_size, void* d_ws, size_t ws_size,
                              hipStream_t stream) {
    const float* x     = (const float*)d_in[0];
    const float* core0 = (const float*)d_in[1];
    const float* cores = (const float*)d_in[2];
    const float* cls   = (const float*)d_in[3];
    float* out = (float*)d_out;

    const int C = (NS + LCH - 1) / LCH;        // 98
    unsigned* pbuf = (unsigned*)d_ws;          // C*Bsz*50 dwords = 40.1 MB
    float*    lbuf = (float*)(pbuf + (size_t)C * 50 * Bsz);

    hipLaunchKernelGGL(chunk_kernel, dim3(Bsz / 128, C), dim3(256),
                       0, stream, x, cores, pbuf, lbuf);
    hipLaunchKernelGGL(combine_kernel, dim3(Bsz / 16), dim3(256),
                       0, stream, x, core0, cls, pbuf, lbuf, out, C);
}

// Round 15
// 80.823 us; speedup vs baseline: 1.4804x; 1.4622x over previous
//
#include <hip/hip_runtime.h>

// MPS classifier: logits[b,o] = (v/||v||)·cls[o] + log||v||,
//   v = head0(b) · M_1(b) · ... · M_783(b),  M_n = A_n + x[b,n]*(B_n - A_n).
// Chain associative; normalizations telescope.
//
// K1 (chunk_kernel, == r13, ~40us): f16 chain (v_pk_fma_f16 on raw
//   `unsigned` f16x2 bit patterns), 2 lanes/sample, [5][5] arrays (the only
//   never-spilled shape), L=8 (C=98), launch_bounds(256,4). Weights
//   fused-converted to LDS, exact x2.0 pre-scale (lbuf -= ns*ln2).
//   Output layout now [c][sample_block4][4][50] f16-packed dwords so a K2
//   wave's 4 samples are 800B contiguous.
// K2 (combine_kernel): the register prefetch ring is DEAD (r12-r14: the
//   compiler sinks __restrict loads to use; 1836cy/chunk of exposed
//   latency). Replaced with an explicit LDS pipeline the compiler cannot
//   sink: per wave, ONE global_load_lds_dwordx4 stages a chunk (800B) into
//   a depth-8 LDS ring; consume after counted `s_waitcnt vmcnt(7)` (never
//   0 until the tail). lbuf is pre-summed (order-independent) by 16 lanes
//   before staging so no other global loads pollute the vmcnt counting.
//   512 blocks x 64 threads (all CUs), launch_bounds(64,1) (no VGPR cap --
//   r11's (64,8) spilled).

constexpr int Bsz = 2048;
constexpr int Nn  = 784;
constexpr int NS  = 783;
constexpr int LCH = 8;      // sites per chunk
constexpr int NCH = (NS + LCH - 1) / LCH;   // 98 chunks

// packed-f16 VOP3P on raw i32 registers (semantics proven r9-r14).
#define PKH_FMA(d, a, b, c) \
  asm("v_pk_fma_f16 %0, %1, %2, %3" : "=v"(d) : "v"(a), "v"(b), "v"(c))
#define PKH_ACC_LO(d, m, s) \
  asm("v_pk_fma_f16 %0, %1, %2, %0 op_sel:[0,0,0] op_sel_hi:[1,0,1]" \
      : "+v"(d) : "v"(m), "v"(s))
#define PKH_ACC_HI(d, m, s) \
  asm("v_pk_fma_f16 %0, %1, %2, %0 op_sel:[0,1,0] op_sel_hi:[1,1,1]" \
      : "+v"(d) : "v"(m), "v"(s))
#define PKH_MUL_LO(d, m, s) \
  asm("v_pk_mul_f16 %0, %1, %2 op_sel:[0,0] op_sel_hi:[1,0]" \
      : "=v"(d) : "v"(m), "v"(s))
// f16 (bits[15:0] of u) -> f32, opaque to the optimizer
#define CVT_H2F(f, u) asm("v_cvt_f32_f16 %0, %1" : "=v"(f) : "v"(u))

__device__ __forceinline__ unsigned short f2h_bits(float f) {
    union { _Float16 h; unsigned short u; } c;
    c.h = (_Float16)f;
    return c.u;
}
__device__ __forceinline__ float hlo(unsigned u) {
    union { unsigned short s; _Float16 h; } c;
    c.s = (unsigned short)(u & 0xffff);
    return (float)c.h;
}
__device__ __forceinline__ float hhi(unsigned u) {
    union { unsigned short s; _Float16 h; } c;
    c.s = (unsigned short)(u >> 16);
    return (float)c.h;
}

// dst(5x10) = src(5x10) * M(site); M blended row-pair at a time from LDS.
__device__ __forceinline__ void site_step(const unsigned* __restrict__ ws,
                                          const unsigned x2,
                                          const unsigned (&src)[5][5],
                                          unsigned (&dst)[5][5]) {
#pragma unroll
    for (int ip = 0; ip < 5; ++ip) {
        unsigned m[10];
        const uint4* w4 = (const uint4*)(ws + ip * 20);
#pragma unroll
        for (int t = 0; t < 5; ++t) {
            const uint4 w = w4[t];
            PKH_FMA(m[2 * t],     w.y, x2, w.x);
            PKH_FMA(m[2 * t + 1], w.w, x2, w.z);
        }
#pragma unroll
        for (int r = 0; r < 5; ++r) {
            if (ip == 0) {
#pragma unroll
                for (int q = 0; q < 5; ++q) PKH_MUL_LO(dst[r][q], m[q], src[r][0]);
            } else {
#pragma unroll
                for (int q = 0; q < 5; ++q) PKH_ACC_LO(dst[r][q], m[q], src[r][ip]);
            }
#pragma unroll
            for (int q = 0; q < 5; ++q) PKH_ACC_HI(dst[r][q], m[5 + q], src[r][ip]);
        }
    }
}

// ---------------- K1: f16 chain, 2 lanes per sample, L=8 ------------------
__global__ __launch_bounds__(256, 4) void chunk_kernel(
    const float* __restrict__ x, const float* __restrict__ cores,
    unsigned* __restrict__ pbuf, float* __restrict__ lbuf) {
    __shared__ unsigned s_w[LCH * 100];
    __shared__ float    s_x[128 * 9];

    const int c   = blockIdx.y;
    const int n0  = 1 + c * LCH;
    const int n1  = min(n0 + LCH, Nn);
    const int ns  = n1 - n0;
    const int tid = (int)threadIdx.x;
    const int b0  = (int)blockIdx.x * 128;

    for (int e = tid; e < ns * 50; e += 256) {
        const int k = e / 50, s = e - k * 50;
        const int i = s / 5, q = s - i * 5;
        const float* g = cores + (size_t)(n0 - 1 + k) * 200 + i * 20 + 2 * q;
        const float a0 = g[0], a1 = g[1], bb0 = g[10], bb1 = g[11];
        const unsigned A = ((unsigned)f2h_bits(2.f * a1) << 16) | f2h_bits(2.f * a0);
        const unsigned D = ((unsigned)f2h_bits(2.f * (bb1 - a1)) << 16) |
                           f2h_bits(2.f * (bb0 - a0));
        s_w[k * 100 + 2 * s]     = A;
        s_w[k * 100 + 2 * s + 1] = D;
    }
    for (int e = tid; e < 128 * 8; e += 256) {
        const int bl = e >> 3, k = e & 7;
        if (k < ns) s_x[bl * 9 + k] = x[(size_t)(b0 + bl) * Nn + n0 + k];
    }
    __syncthreads();

    const int h = tid & 1;
    const int u = tid >> 1;
    const int b = b0 + u;
    const float* __restrict__ xs = s_x + u * 9;

    unsigned p[5][5], q2[5][5];
    {
        const unsigned short xb = f2h_bits(xs[0]);
        const unsigned x2 = ((unsigned)xb << 16) | xb;
#pragma unroll
        for (int r = 0; r < 5; ++r)
#pragma unroll
            for (int q = 0; q < 5; ++q) {
                const unsigned A = s_w[(5 * h + r) * 10 + 2 * q];
                const unsigned D = s_w[(5 * h + r) * 10 + 2 * q + 1];
                PKH_FMA(p[r][q], D, x2, A);
            }
    }
    int k = 1;
    while (k + 1 < ns) {
        {
            const unsigned short xb = f2h_bits(xs[k]);
            site_step(s_w + k * 100, ((unsigned)xb << 16) | xb, p, q2);
        }
        {
            const unsigned short xb = f2h_bits(xs[k + 1]);
            site_step(s_w + (k + 1) * 100, ((unsigned)xb << 16) | xb, q2, p);
        }
        k += 2;
    }
    if (k < ns) {
        const unsigned short xb = f2h_bits(xs[k]);
        site_step(s_w + k * 100, ((unsigned)xb << 16) | xb, p, q2);
#pragma unroll
        for (int r = 0; r < 5; ++r)
#pragma unroll
            for (int q = 0; q < 5; ++q) p[r][q] = q2[r][q];
    }

    float ss = 0.f;
#pragma unroll
    for (int r = 0; r < 5; ++r)
#pragma unroll
        for (int q = 0; q < 5; ++q) {
            const float lo = hlo(p[r][q]), hi = hhi(p[r][q]);
            ss = fmaf(lo, lo, ss);
            ss = fmaf(hi, hi, ss);
        }
    ss += __shfl_xor(ss, 1);
    ss = fmaxf(ss, 1e-30f);
    const float rin = rsqrtf(ss);
    if (h == 0)
        lbuf[(size_t)c * Bsz + b] = 0.5f * __logf(ss) - (float)ns * 0.69314718056f;

    // store packed f16 dwords, layout [c][b>>2][ (b&3)*50 + (5h+r)*5 + q ]
    unsigned* dst = pbuf + ((size_t)c * 512 + (b >> 2)) * 200 + (b & 3) * 50;
#pragma unroll
    for (int r = 0; r < 5; ++r)
#pragma unroll
        for (int q = 0; q < 5; ++q) {
            const float lo = hlo(p[r][q]) * rin;
            const float hi = hhi(p[r][q]) * rin;
            dst[(5 * h + r) * 5 + q] =
                ((unsigned)f2h_bits(hi) << 16) | f2h_bits(lo);
        }
}

// ---------------- K2: combine via explicit LDS pipeline -------------------
// 64-thread blocks, 4 samples each, 512 blocks. Depth-8 LDS ring, one
// global_load_lds_dwordx4 per chunk per wave, counted vmcnt.
__global__ __launch_bounds__(64, 1) void combine_kernel(
    const float* __restrict__ x, const float* __restrict__ core0,
    const float* __restrict__ cls, const unsigned* __restrict__ pbuf,
    const float* __restrict__ lbuf, float* __restrict__ out, int C) {
    __shared__ __align__(16) unsigned ring[8][256];

    const int tid   = (int)threadIdx.x;
    const int j     = tid & 15;
    const int jj    = (j < 10) ? j : 9;
    const int gbase = tid & 48;
    const int sl    = tid >> 4;               // sample slot 0..3
    const int b     = (int)blockIdx.x * 4 + sl;
    const int qoff  = jj >> 1;
    const unsigned sh = (unsigned)(jj & 1) * 16;

    // ---- v init + lbuf pre-sum (all global loads BEFORE staging) ----
    float v[10];
    const float x0 = x[(size_t)b * Nn];
#pragma unroll
    for (int i = 0; i < 10; ++i) {
        const float c0 = core0[i], c1 = core0[10 + i];
        v[i] = fmaf(x0, c1 - c0, c0);
    }
    float llog = 0.f;
    for (int cc = j; cc < C; cc += 16)        // independent, overlapped
        llog += lbuf[(size_t)cc * Bsz + b];
    llog += __shfl_xor(llog, 1);
    llog += __shfl_xor(llog, 2);
    llog += __shfl_xor(llog, 4);
    llog += __shfl_xor(llog, 8);

    // ---- staging setup: lane stages dwords [l*4, l*4+4) of the 200 ----
    const int flat = (tid * 4 <= 196) ? tid * 4 : 196;   // clamp, 16B aligned
    const unsigned* gsrc0 = pbuf + (size_t)blockIdx.x * 200 + flat;
    const size_t cstride = (size_t)512 * 200;            // dwords per chunk

#define STAGE(cc)                                                          \
    __builtin_amdgcn_global_load_lds(                                      \
        (const __attribute__((address_space(1))) unsigned*)(gsrc0 +        \
            (size_t)(cc) * cstride),                                       \
        (__attribute__((address_space(3))) unsigned*)&ring[(cc) & 7][0],   \
        16, 0, 0)

#pragma unroll
    for (int d = 0; d < 8; ++d) STAGE(d);     // prologue: 8 in flight

    const int lbase = sl * 50 + qoff;
    for (int c = 0; c < C; ++c) {
        const int d = c & 7;
        if (c + 8 <= C - 1) {
            asm volatile("s_waitcnt vmcnt(7)" ::: "memory");
        } else {
            asm volatile("s_waitcnt vmcnt(0)" ::: "memory");
        }
        __builtin_amdgcn_sched_barrier(0);

        float acc = 0.f;
#pragma unroll
        for (int i = 0; i < 10; ++i) {
            unsigned ud = ring[d][lbase + i * 5] >> sh;
            float wv;
            CVT_H2F(wv, ud);
            acc = fmaf(v[i], wv, acc);
        }
        if (j >= 10) acc = 0.f;
        if ((c & 7) == 7 || c == C - 1) {     // deferred renorm
            float s = acc * acc;
            s += __shfl_xor(s, 1);
            s += __shfl_xor(s, 2);
            s += __shfl_xor(s, 4);
            s += __shfl_xor(s, 8);
            s = fmaxf(s, 1e-30f);
            llog += 0.5f * __logf(s);
            acc *= rsqrtf(s);
        }
#pragma unroll
        for (int i = 0; i < 10; ++i) v[i] = __shfl(acc, gbase + i);

        if (c + 8 < C) STAGE(c + 8);          // refill the slot just freed
    }
#undef STAGE

    if (j < 10) {
        float acc = llog;
#pragma unroll
        for (int i = 0; i < 10; ++i) acc = fmaf(v[i], cls[j * 10 + i], acc);
        out[(size_t)b * 10 + j] = acc;
    }
}

// ---------------- launch ----------------
extern "C" void kernel_launch(void* const* d_in, const int* in_sizes, int n_in,
                              void* d_out, int out_size, void* d_ws, size_t ws_size,
                              hipStream_t stream) {
    const float* x     = (const float*)d_in[0];
    const float* core0 = (const float*)d_in[1];
    const float* cores = (const float*)d_in[2];
    const float* cls   = (const float*)d_in[3];
    float* out = (float*)d_out;

    const int C = NCH;                          // 98
    unsigned* pbuf = (unsigned*)d_ws;           // C*512*200 dwords = 40.1 MB
    float*    lbuf = (float*)(pbuf + (size_t)C * 512 * 200);

    hipLaunchKernelGGL(chunk_kernel, dim3(Bsz / 128, C), dim3(256),
                       0, stream, x, cores, pbuf, lbuf);
    hipLaunchKernelGGL(combine_kernel, dim3(Bsz / 4), dim3(64),
                       0, stream, x, core0, cls, pbuf, lbuf, out, C);
}

// Round 16
// 72.740 us; speedup vs baseline: 1.6449x; 1.1111x over previous
//
#include <hip/hip_runtime.h>

// MPS classifier: logits[b,o] = (v/||v||)·cls[o] + log||v||,
//   v = head0(b) · M_1(b) · ... · M_783(b),  M_n = A_n + x[b,n]*(B_n - A_n).
// Chain associative; normalizations telescope.
//
// K1 (chunk_kernel): f16 chain (v_pk_fma_f16 on raw `unsigned` f16x2 bit
//   patterns), 2 lanes/sample, [5][5] arrays (never-spilled shape),
//   L=16 sites/chunk (C=49) -- L doubled vs r15 to HALVE K2's serial
//   chunk chain (K2 is pure serial latency: 512 concurrent waves, wall
//   time = C x critical-path). Store expression kept in r13's exact
//   arithmetic form ((c*Bsz+b)*50): r15's algebraically-identical
//   rewrite perturbed codegen (VGPR 56->36, +6us).
//   Weights fused-converted to LDS, exact x2.0 pre-scale (lbuf -= ns*ln2).
// K2 (combine_kernel): r15's explicit LDS pipeline (compiler cannot sink
//   async DMA): one global_load_lds_dwordx4 per chunk per wave into a
//   depth-8 LDS ring, counted `s_waitcnt vmcnt(7)`; lbuf pre-summed before
//   staging. 512 blocks x 64 threads, launch_bounds(64,1).

constexpr int Bsz = 2048;
constexpr int Nn  = 784;
constexpr int NS  = 783;
constexpr int LCH = 16;     // sites per chunk
constexpr int NCH = (NS + LCH - 1) / LCH;   // 49 chunks

// packed-f16 VOP3P on raw i32 registers (semantics proven r9-r15).
#define PKH_FMA(d, a, b, c) \
  asm("v_pk_fma_f16 %0, %1, %2, %3" : "=v"(d) : "v"(a), "v"(b), "v"(c))
#define PKH_ACC_LO(d, m, s) \
  asm("v_pk_fma_f16 %0, %1, %2, %0 op_sel:[0,0,0] op_sel_hi:[1,0,1]" \
      : "+v"(d) : "v"(m), "v"(s))
#define PKH_ACC_HI(d, m, s) \
  asm("v_pk_fma_f16 %0, %1, %2, %0 op_sel:[0,1,0] op_sel_hi:[1,1,1]" \
      : "+v"(d) : "v"(m), "v"(s))
#define PKH_MUL_LO(d, m, s) \
  asm("v_pk_mul_f16 %0, %1, %2 op_sel:[0,0] op_sel_hi:[1,0]" \
      : "=v"(d) : "v"(m), "v"(s))
// f16 (bits[15:0] of u) -> f32, opaque to the optimizer
#define CVT_H2F(f, u) asm("v_cvt_f32_f16 %0, %1" : "=v"(f) : "v"(u))

__device__ __forceinline__ unsigned short f2h_bits(float f) {
    union { _Float16 h; unsigned short u; } c;
    c.h = (_Float16)f;
    return c.u;
}
__device__ __forceinline__ float hlo(unsigned u) {
    union { unsigned short s; _Float16 h; } c;
    c.s = (unsigned short)(u & 0xffff);
    return (float)c.h;
}
__device__ __forceinline__ float hhi(unsigned u) {
    union { unsigned short s; _Float16 h; } c;
    c.s = (unsigned short)(u >> 16);
    return (float)c.h;
}

// dst(5x10) = src(5x10) * M(site); M blended row-pair at a time from LDS.
__device__ __forceinline__ void site_step(const unsigned* __restrict__ ws,
                                          const unsigned x2,
                                          const unsigned (&src)[5][5],
                                          unsigned (&dst)[5][5]) {
#pragma unroll
    for (int ip = 0; ip < 5; ++ip) {
        unsigned m[10];
        const uint4* w4 = (const uint4*)(ws + ip * 20);
#pragma unroll
        for (int t = 0; t < 5; ++t) {
            const uint4 w = w4[t];
            PKH_FMA(m[2 * t],     w.y, x2, w.x);
            PKH_FMA(m[2 * t + 1], w.w, x2, w.z);
        }
#pragma unroll
        for (int r = 0; r < 5; ++r) {
            if (ip == 0) {
#pragma unroll
                for (int q = 0; q < 5; ++q) PKH_MUL_LO(dst[r][q], m[q], src[r][0]);
            } else {
#pragma unroll
                for (int q = 0; q < 5; ++q) PKH_ACC_LO(dst[r][q], m[q], src[r][ip]);
            }
#pragma unroll
            for (int q = 0; q < 5; ++q) PKH_ACC_HI(dst[r][q], m[5 + q], src[r][ip]);
        }
    }
}

// ---------------- K1: f16 chain, 2 lanes per sample, L=16 -----------------
__global__ __launch_bounds__(256, 4) void chunk_kernel(
    const float* __restrict__ x, const float* __restrict__ cores,
    unsigned* __restrict__ pbuf, float* __restrict__ lbuf) {
    __shared__ unsigned s_w[LCH * 100];  // per-site f16 {A,D} dwords (6.4 KB)
    __shared__ float    s_x[128 * 17];   // x slice, stride 17 (8.7 KB)

    const int c   = blockIdx.y;
    const int n0  = 1 + c * LCH;
    const int n1  = min(n0 + LCH, Nn);
    const int ns  = n1 - n0;
    const int tid = (int)threadIdx.x;
    const int b0  = (int)blockIdx.x * 128;

    for (int e = tid; e < ns * 50; e += 256) {
        const int k = e / 50, s = e - k * 50;
        const int i = s / 5, q = s - i * 5;
        const float* g = cores + (size_t)(n0 - 1 + k) * 200 + i * 20 + 2 * q;
        const float a0 = g[0], a1 = g[1], bb0 = g[10], bb1 = g[11];
        const unsigned A = ((unsigned)f2h_bits(2.f * a1) << 16) | f2h_bits(2.f * a0);
        const unsigned D = ((unsigned)f2h_bits(2.f * (bb1 - a1)) << 16) |
                           f2h_bits(2.f * (bb0 - a0));
        s_w[k * 100 + 2 * s]     = A;
        s_w[k * 100 + 2 * s + 1] = D;
    }
    for (int e = tid; e < 128 * 16; e += 256) {
        const int bl = e >> 4, k = e & 15;
        if (k < ns) s_x[bl * 17 + k] = x[(size_t)(b0 + bl) * Nn + n0 + k];
    }
    __syncthreads();

    const int h = tid & 1;
    const int u = tid >> 1;
    const int b = b0 + u;
    const float* __restrict__ xs = s_x + u * 17;

    unsigned p[5][5], q2[5][5];
    {   // first site: P = 2*M (rows 5h..5h+4)
        const unsigned short xb = f2h_bits(xs[0]);
        const unsigned x2 = ((unsigned)xb << 16) | xb;
#pragma unroll
        for (int r = 0; r < 5; ++r)
#pragma unroll
            for (int q = 0; q < 5; ++q) {
                const unsigned A = s_w[(5 * h + r) * 10 + 2 * q];
                const unsigned D = s_w[(5 * h + r) * 10 + 2 * q + 1];
                PKH_FMA(p[r][q], D, x2, A);
            }
    }
    int k = 1;
    while (k + 1 < ns) {
        {
            const unsigned short xb = f2h_bits(xs[k]);
            site_step(s_w + k * 100, ((unsigned)xb << 16) | xb, p, q2);
        }
        {
            const unsigned short xb = f2h_bits(xs[k + 1]);
            site_step(s_w + (k + 1) * 100, ((unsigned)xb << 16) | xb, q2, p);
        }
        k += 2;
    }
    if (k < ns) {
        const unsigned short xb = f2h_bits(xs[k]);
        site_step(s_w + k * 100, ((unsigned)xb << 16) | xb, p, q2);
#pragma unroll
        for (int r = 0; r < 5; ++r)
#pragma unroll
            for (int q = 0; q < 5; ++q) p[r][q] = q2[r][q];
    }

    float ss = 0.f;
#pragma unroll
    for (int r = 0; r < 5; ++r)
#pragma unroll
        for (int q = 0; q < 5; ++q) {
            const float lo = hlo(p[r][q]), hi = hhi(p[r][q]);
            ss = fmaf(lo, lo, ss);
            ss = fmaf(hi, hi, ss);
        }
    ss += __shfl_xor(ss, 1);
    ss = fmaxf(ss, 1e-30f);
    const float rin = rsqrtf(ss);
    if (h == 0)
        lbuf[(size_t)c * Bsz + b] = 0.5f * __logf(ss) - (float)ns * 0.69314718056f;

    // store packed f16 dwords: pbuf[(c*Bsz+b)*50 + (5h+r)*5 + q]  (r13 form)
    unsigned* dst = pbuf + ((size_t)c * Bsz + b) * 50;
#pragma unroll
    for (int r = 0; r < 5; ++r)
#pragma unroll
        for (int q = 0; q < 5; ++q) {
            const float lo = hlo(p[r][q]) * rin;
            const float hi = hhi(p[r][q]) * rin;
            dst[(5 * h + r) * 5 + q] =
                ((unsigned)f2h_bits(hi) << 16) | f2h_bits(lo);
        }
}

// ---------------- K2: combine via explicit LDS pipeline -------------------
// 64-thread blocks, 4 samples each, 512 blocks. Depth-8 LDS ring, one
// global_load_lds_dwordx4 per chunk per wave, counted vmcnt.
__global__ __launch_bounds__(64, 1) void combine_kernel(
    const float* __restrict__ x, const float* __restrict__ core0,
    const float* __restrict__ cls, const unsigned* __restrict__ pbuf,
    const float* __restrict__ lbuf, float* __restrict__ out, int C) {
    __shared__ __align__(16) unsigned ring[8][256];

    const int tid   = (int)threadIdx.x;
    const int j     = tid & 15;
    const int jj    = (j < 10) ? j : 9;
    const int gbase = tid & 48;
    const int sl    = tid >> 4;               // sample slot 0..3
    const int b     = (int)blockIdx.x * 4 + sl;
    const int qoff  = jj >> 1;
    const unsigned sh = (unsigned)(jj & 1) * 16;

    // ---- v init + lbuf pre-sum (all global loads BEFORE staging) ----
    float v[10];
    const float x0 = x[(size_t)b * Nn];
#pragma unroll
    for (int i = 0; i < 10; ++i) {
        const float c0 = core0[i], c1 = core0[10 + i];
        v[i] = fmaf(x0, c1 - c0, c0);
    }
    float llog = 0.f;
    for (int cc = j; cc < C; cc += 16)        // independent, overlapped
        llog += lbuf[(size_t)cc * Bsz + b];
    llog += __shfl_xor(llog, 1);
    llog += __shfl_xor(llog, 2);
    llog += __shfl_xor(llog, 4);
    llog += __shfl_xor(llog, 8);

    // ---- staging: lane stages dwords [l*4, l*4+4) of the wave's 200 ----
    const int flat = (tid * 4 <= 196) ? tid * 4 : 196;   // clamp, 16B aligned
    const unsigned* gsrc0 = pbuf + (size_t)blockIdx.x * 200 + flat;
    const size_t cstride = (size_t)Bsz * 50;             // dwords per chunk

#define STAGE(cc)                                                          \
    __builtin_amdgcn_global_load_lds(                                      \
        (const __attribute__((address_space(1))) unsigned*)(gsrc0 +        \
            (size_t)(cc) * cstride),                                       \
        (__attribute__((address_space(3))) unsigned*)&ring[(cc) & 7][0],   \
        16, 0, 0)

#pragma unroll
    for (int d = 0; d < 8; ++d) STAGE(d);     // prologue: 8 in flight

    const int lbase = sl * 50 + qoff;
    for (int c = 0; c < C; ++c) {
        const int d = c & 7;
        if (c + 8 <= C - 1) {
            asm volatile("s_waitcnt vmcnt(7)" ::: "memory");
        } else {
            asm volatile("s_waitcnt vmcnt(0)" ::: "memory");
        }
        __builtin_amdgcn_sched_barrier(0);

        float acc = 0.f;
#pragma unroll
        for (int i = 0; i < 10; ++i) {
            unsigned ud = ring[d][lbase + i * 5] >> sh;
            float wv;
            CVT_H2F(wv, ud);
            acc = fmaf(v[i], wv, acc);
        }
        if (j >= 10) acc = 0.f;
        if ((c & 7) == 7 || c == C - 1) {     // deferred renorm
            float s = acc * acc;
            s += __shfl_xor(s, 1);
            s += __shfl_xor(s, 2);
            s += __shfl_xor(s, 4);
            s += __shfl_xor(s, 8);
            s = fmaxf(s, 1e-30f);
            llog += 0.5f * __logf(s);
            acc *= rsqrtf(s);
        }
#pragma unroll
        for (int i = 0; i < 10; ++i) v[i] = __shfl(acc, gbase + i);

        if (c + 8 < C) STAGE(c + 8);          // refill the slot just freed
    }
#undef STAGE

    if (j < 10) {
        float acc = llog;
#pragma unroll
        for (int i = 0; i < 10; ++i) acc = fmaf(v[i], cls[j * 10 + i], acc);
        out[(size_t)b * 10 + j] = acc;
    }
}

// ---------------- launch ----------------
extern "C" void kernel_launch(void* const* d_in, const int* in_sizes, int n_in,
                              void* d_out, int out_size, void* d_ws, size_t ws_size,
                              hipStream_t stream) {
    const float* x     = (const float*)d_in[0];
    const float* core0 = (const float*)d_in[1];
    const float* cores = (const float*)d_in[2];
    const float* cls   = (const float*)d_in[3];
    float* out = (float*)d_out;

    const int C = NCH;                          // 49
    unsigned* pbuf = (unsigned*)d_ws;           // C*Bsz*50 dwords = 20.1 MB
    float*    lbuf = (float*)(pbuf + (size_t)C * Bsz * 50);

    hipLaunchKernelGGL(chunk_kernel, dim3(Bsz / 128, C), dim3(256),
                       0, stream, x, cores, pbuf, lbuf);
    hipLaunchKernelGGL(combine_kernel, dim3(Bsz / 4), dim3(64),
                       0, stream, x, core0, cls, pbuf, lbuf, out, C);
}

// Round 18
// 72.188 us; speedup vs baseline: 1.6575x; 1.0077x over previous
//
#include <hip/hip_runtime.h>

// MPS classifier: logits[b,o] = (v/||v||)·cls[o] + log||v||,
//   v = head0(b) · M_1(b) · ... · M_783(b),  M_n = A_n + x[b,n]*(B_n - A_n).
// Chain associative; normalizations telescope.
//
// K1 (chunk_kernel): f16 chain (v_pk_fma_f16 on raw `unsigned` f16x2 bit
//   patterns), 2 lanes/sample, [5][5] arrays, L=16 (C=49), r16 code with
//   launch_bounds(256,3): grid (784 blocks) limits occupancy to ~3
//   blocks/CU regardless, so raising the VGPR cap 128->170 is free
//   headroom against the erratic VGPR-32 allocator collapse.
// K2 (combine_kernel): explicit LDS pipeline, now DEPTH-7 on the 8-slot
//   ring. r15-r17 used depth-8: STAGE(c+8) overwrites the SAME slot being
//   consumed ((c+8)&7==c&7) -- a timing-marginal race that caused r17's
//   post-timing divergence (absmax 64 under replay contention). Depth-7
//   targets the slot consumed LAST iteration (~700cy slack). Counted
//   s_waitcnt vmcnt(6); lbuf pre-summed before staging. 512x64 blocks.

constexpr int Bsz = 2048;
constexpr int Nn  = 784;
constexpr int NS  = 783;
constexpr int LCH = 16;     // sites per chunk
constexpr int NCH = (NS + LCH - 1) / LCH;   // 49 chunks

// packed-f16 VOP3P on raw i32 registers (semantics proven r9-r17).
#define PKH_FMA(d, a, b, c) \
  asm("v_pk_fma_f16 %0, %1, %2, %3" : "=v"(d) : "v"(a), "v"(b), "v"(c))
#define PKH_ACC_LO(d, m, s) \
  asm("v_pk_fma_f16 %0, %1, %2, %0 op_sel:[0,0,0] op_sel_hi:[1,0,1]" \
      : "+v"(d) : "v"(m), "v"(s))
#define PKH_ACC_HI(d, m, s) \
  asm("v_pk_fma_f16 %0, %1, %2, %0 op_sel:[0,1,0] op_sel_hi:[1,1,1]" \
      : "+v"(d) : "v"(m), "v"(s))
#define PKH_MUL_LO(d, m, s) \
  asm("v_pk_mul_f16 %0, %1, %2 op_sel:[0,0] op_sel_hi:[1,0]" \
      : "=v"(d) : "v"(m), "v"(s))
// f16 (bits[15:0] of u) -> f32, opaque to the optimizer
#define CVT_H2F(f, u) asm("v_cvt_f32_f16 %0, %1" : "=v"(f) : "v"(u))

__device__ __forceinline__ unsigned short f2h_bits(float f) {
    union { _Float16 h; unsigned short u; } c;
    c.h = (_Float16)f;
    return c.u;
}
__device__ __forceinline__ float hlo(unsigned u) {
    union { unsigned short s; _Float16 h; } c;
    c.s = (unsigned short)(u & 0xffff);
    return (float)c.h;
}
__device__ __forceinline__ float hhi(unsigned u) {
    union { unsigned short s; _Float16 h; } c;
    c.s = (unsigned short)(u >> 16);
    return (float)c.h;
}

// dst(5x10) = src(5x10) * M(site); M blended row-pair at a time from LDS.
__device__ __forceinline__ void site_step(const unsigned* __restrict__ ws,
                                          const unsigned x2,
                                          const unsigned (&src)[5][5],
                                          unsigned (&dst)[5][5]) {
#pragma unroll
    for (int ip = 0; ip < 5; ++ip) {
        unsigned m[10];
        const uint4* w4 = (const uint4*)(ws + ip * 20);
#pragma unroll
        for (int t = 0; t < 5; ++t) {
            const uint4 w = w4[t];
            PKH_FMA(m[2 * t],     w.y, x2, w.x);
            PKH_FMA(m[2 * t + 1], w.w, x2, w.z);
        }
#pragma unroll
        for (int r = 0; r < 5; ++r) {
            if (ip == 0) {
#pragma unroll
                for (int q = 0; q < 5; ++q) PKH_MUL_LO(dst[r][q], m[q], src[r][0]);
            } else {
#pragma unroll
                for (int q = 0; q < 5; ++q) PKH_ACC_LO(dst[r][q], m[q], src[r][ip]);
            }
#pragma unroll
            for (int q = 0; q < 5; ++q) PKH_ACC_HI(dst[r][q], m[5 + q], src[r][ip]);
        }
    }
}

// ---------------- K1: f16 chain, 2 lanes per sample, L=16 -----------------
__global__ __launch_bounds__(256, 3) void chunk_kernel(
    const float* __restrict__ x, const float* __restrict__ cores,
    unsigned* __restrict__ pbuf, float* __restrict__ lbuf) {
    __shared__ unsigned s_w[LCH * 100];  // per-site f16 {A,D} dwords
    __shared__ float    s_x[128 * 17];   // x slice, stride 17

    const int c   = blockIdx.y;
    const int n0  = 1 + c * LCH;
    const int n1  = min(n0 + LCH, Nn);
    const int ns  = n1 - n0;
    const int tid = (int)threadIdx.x;
    const int b0  = (int)blockIdx.x * 128;

    for (int e = tid; e < ns * 50; e += 256) {
        const int k = e / 50, s = e - k * 50;
        const int i = s / 5, q = s - i * 5;
        const float* g = cores + (size_t)(n0 - 1 + k) * 200 + i * 20 + 2 * q;
        const float a0 = g[0], a1 = g[1], bb0 = g[10], bb1 = g[11];
        const unsigned A = ((unsigned)f2h_bits(2.f * a1) << 16) | f2h_bits(2.f * a0);
        const unsigned D = ((unsigned)f2h_bits(2.f * (bb1 - a1)) << 16) |
                           f2h_bits(2.f * (bb0 - a0));
        s_w[k * 100 + 2 * s]     = A;
        s_w[k * 100 + 2 * s + 1] = D;
    }
    for (int e = tid; e < 128 * 16; e += 256) {
        const int bl = e >> 4, k = e & 15;
        if (k < ns) s_x[bl * 17 + k] = x[(size_t)(b0 + bl) * Nn + n0 + k];
    }
    __syncthreads();

    const int h = tid & 1;
    const int u = tid >> 1;
    const int b = b0 + u;
    const float* __restrict__ xs = s_x + u * 17;

    unsigned p[5][5], q2[5][5];
    {   // first site: P = 2*M (rows 5h..5h+4)
        const unsigned short xb = f2h_bits(xs[0]);
        const unsigned x2 = ((unsigned)xb << 16) | xb;
#pragma unroll
        for (int r = 0; r < 5; ++r)
#pragma unroll
            for (int q = 0; q < 5; ++q) {
                const unsigned A = s_w[(5 * h + r) * 10 + 2 * q];
                const unsigned D = s_w[(5 * h + r) * 10 + 2 * q + 1];
                PKH_FMA(p[r][q], D, x2, A);
            }
    }
    int k = 1;
    while (k + 1 < ns) {
        {
            const unsigned short xb = f2h_bits(xs[k]);
            site_step(s_w + k * 100, ((unsigned)xb << 16) | xb, p, q2);
        }
        {
            const unsigned short xb = f2h_bits(xs[k + 1]);
            site_step(s_w + (k + 1) * 100, ((unsigned)xb << 16) | xb, q2, p);
        }
        k += 2;
    }
    if (k < ns) {
        const unsigned short xb = f2h_bits(xs[k]);
        site_step(s_w + k * 100, ((unsigned)xb << 16) | xb, p, q2);
#pragma unroll
        for (int r = 0; r < 5; ++r)
#pragma unroll
            for (int q = 0; q < 5; ++q) p[r][q] = q2[r][q];
    }

    float ss = 0.f;
#pragma unroll
    for (int r = 0; r < 5; ++r)
#pragma unroll
        for (int q = 0; q < 5; ++q) {
            const float lo = hlo(p[r][q]), hi = hhi(p[r][q]);
            ss = fmaf(lo, lo, ss);
            ss = fmaf(hi, hi, ss);
        }
    ss += __shfl_xor(ss, 1);
    ss = fmaxf(ss, 1e-30f);
    const float rin = rsqrtf(ss);
    if (h == 0)
        lbuf[(size_t)c * Bsz + b] = 0.5f * __logf(ss) - (float)ns * 0.69314718056f;

    // store packed f16 dwords: pbuf[(c*Bsz+b)*50 + (5h+r)*5 + q]
    unsigned* dst = pbuf + ((size_t)c * Bsz + b) * 50;
#pragma unroll
    for (int r = 0; r < 5; ++r)
#pragma unroll
        for (int q = 0; q < 5; ++q) {
            const float lo = hlo(p[r][q]) * rin;
            const float hi = hhi(p[r][q]) * rin;
            dst[(5 * h + r) * 5 + q] =
                ((unsigned)f2h_bits(hi) << 16) | f2h_bits(lo);
        }
}

// ---------------- K2: combine via explicit LDS pipeline (depth-7) ---------
__global__ __launch_bounds__(64, 1) void combine_kernel(
    const float* __restrict__ x, const float* __restrict__ core0,
    const float* __restrict__ cls, const unsigned* __restrict__ pbuf,
    const float* __restrict__ lbuf, float* __restrict__ out, int C) {
    __shared__ __align__(16) unsigned ring[8][256];

    const int tid   = (int)threadIdx.x;
    const int j     = tid & 15;
    const int jj    = (j < 10) ? j : 9;
    const int gbase = tid & 48;
    const int sl    = tid >> 4;               // sample slot 0..3
    const int b     = (int)blockIdx.x * 4 + sl;
    const int qoff  = jj >> 1;
    const unsigned sh = (unsigned)(jj & 1) * 16;

    // ---- v init + lbuf pre-sum (all global loads BEFORE staging) ----
    float v[10];
    const float x0 = x[(size_t)b * Nn];
#pragma unroll
    for (int i = 0; i < 10; ++i) {
        const float c0 = core0[i], c1 = core0[10 + i];
        v[i] = fmaf(x0, c1 - c0, c0);
    }
    float llog = 0.f;
    for (int cc = j; cc < C; cc += 16)
        llog += lbuf[(size_t)cc * Bsz + b];
    llog += __shfl_xor(llog, 1);
    llog += __shfl_xor(llog, 2);
    llog += __shfl_xor(llog, 4);
    llog += __shfl_xor(llog, 8);

    // ---- staging: lane stages dwords [l*4, l*4+4) of the wave's 200 ----
    const int flat = (tid * 4 <= 196) ? tid * 4 : 196;
    const unsigned* gsrc0 = pbuf + (size_t)blockIdx.x * 200 + flat;
    const size_t cstride = (size_t)Bsz * 50;

#define STAGE(cc)                                                          \
    __builtin_amdgcn_global_load_lds(                                      \
        (const __attribute__((address_space(1))) unsigned*)(gsrc0 +        \
            (size_t)(cc) * cstride),                                       \
        (__attribute__((address_space(3))) unsigned*)&ring[(cc) & 7][0],   \
        16, 0, 0)

#pragma unroll
    for (int d = 0; d < 7; ++d) STAGE(d);     // prologue: 7 in flight

    const int lbase = sl * 50 + qoff;
    for (int c = 0; c < C; ++c) {
        const int d = c & 7;
        if (c + 7 <= C - 1) {
            asm volatile("s_waitcnt vmcnt(6)" ::: "memory");
        } else {
            asm volatile("s_waitcnt vmcnt(0)" ::: "memory");
        }
        __builtin_amdgcn_sched_barrier(0);

        float acc = 0.f;
#pragma unroll
        for (int i = 0; i < 10; ++i) {
            unsigned ud = ring[d][lbase + i * 5] >> sh;
            float wv;
            CVT_H2F(wv, ud);
            acc = fmaf(v[i], wv, acc);
        }
        if (j >= 10) acc = 0.f;
        if ((c & 7) == 7 || c == C - 1) {     // deferred renorm
            float s = acc * acc;
            s += __shfl_xor(s, 1);
            s += __shfl_xor(s, 2);
            s += __shfl_xor(s, 4);
            s += __shfl_xor(s, 8);
            s = fmaxf(s, 1e-30f);
            llog += 0.5f * __logf(s);
            acc *= rsqrtf(s);
        }
#pragma unroll
        for (int i = 0; i < 10; ++i) v[i] = __shfl(acc, gbase + i);

        // refill: targets slot (c+7)&7 = (c-1)&7, consumed LAST iteration
        if (c + 7 < C) STAGE(c + 7);
    }
#undef STAGE

    if (j < 10) {
        float acc = llog;
#pragma unroll
        for (int i = 0; i < 10; ++i) acc = fmaf(v[i], cls[j * 10 + i], acc);
        out[(size_t)b * 10 + j] = acc;
    }
}

// ---------------- launch ----------------
extern "C" void kernel_launch(void* const* d_in, const int* in_sizes, int n_in,
                              void* d_out, int out_size, void* d_ws, size_t ws_size,
                              hipStream_t stream) {
    const float* x     = (const float*)d_in[0];
    const float* core0 = (const float*)d_in[1];
    const float* cores = (const float*)d_in[2];
    const float* cls   = (const float*)d_in[3];
    float* out = (float*)d_out;

    const int C = NCH;                          // 49
    unsigned* pbuf = (unsigned*)d_ws;           // C*Bsz*50 dwords = 20.1 MB
    float*    lbuf = (float*)(pbuf + (size_t)C * Bsz * 50);

    hipLaunchKernelGGL(chunk_kernel, dim3(Bsz / 128, C), dim3(256),
                       0, stream, x, cores, pbuf, lbuf);
    hipLaunchKernelGGL(combine_kernel, dim3(Bsz / 4), dim3(64),
                       0, stream, x, core0, cls, pbuf, lbuf, out, C);
}